// Round 2
// baseline (564.158 us; speedup 1.0000x reference)
//
#include <hip/hip_runtime.h>
#include <hip/hip_bf16.h>

#define C_IN 64
#define H_IN 512
#define W_IN 512
#define D_OUT 128
#define OH 510
#define OW 510

typedef __bf16 bf16x8 __attribute__((ext_vector_type(8)));
typedef float  f32x4  __attribute__((ext_vector_type(4)));
typedef float  f32x2  __attribute__((ext_vector_type(2)));

#define TIN_ELEMS (H_IN * W_IN * C_IN)          // 16,777,216
#define TIN_BYTES (TIN_ELEMS * 2)               // 32 MB
#define WT_BYTES  (9 * D_OUT * C_IN * 2)        // 147,456
#define WS_NEEDED ((size_t)TIN_BYTES + WT_BYTES)

// ---------- pre-pass: kernels [D][C][3][3] fp32 -> wt[kpos][d][c] bf16 ----------
__global__ void prep_weights(const float* __restrict__ w, __bf16* __restrict__ wt) {
    int i = blockIdx.x * blockDim.x + threadIdx.x;
    if (i >= 9 * D_OUT * C_IN) return;
    int c    = i & 63;
    int d    = (i >> 6) & 127;
    int kpos = i >> 13;
    wt[i] = (__bf16)w[((d * C_IN) + c) * 9 + kpos];
}

// ---------- pre-pass: input [c][y][x] fp32 -> tin[y][x][c] bf16 ----------
// block = 256 threads = 256 consecutive px of one row; loop over 8 c-octets.
// Loads coalesced (lane px consecutive for fixed c); stores 16B/lane at 128B
// stride (write-combined in L2/L3).
__global__ void transpose_in(const float* __restrict__ in, __bf16* __restrict__ tin) {
    int b  = blockIdx.x;            // 512*2
    int y  = b >> 1;
    int px = ((b & 1) << 8) + threadIdx.x;
#pragma unroll
    for (int oct = 0; oct < 8; oct++) {
        bf16x8 v;
#pragma unroll
        for (int j = 0; j < 8; j++)
            v[j] = (__bf16)in[(oct * 8 + j) * (H_IN * W_IN) + y * W_IN + px];
        *(bf16x8*)&tin[((y * W_IN) + px) * C_IN + oct * 8] = v;
    }
}

// ---------- main conv: no LDS, no barriers, weights in registers ----------
// Grid: 510 rows x 8 x-tiles of 64 px (last tile overlaps: x0=446).
// Wave w owns d in [32w, 32w+32). A-operand = pixels (M=16 px), B = weights
// (N=16 d) so acc regs hold 4 consecutive px -> float2 epilogue.
__global__ __launch_bounds__(256, 2)
void conv_main(const __bf16* __restrict__ tin, const __bf16* __restrict__ wt,
               const float* __restrict__ bias, float* __restrict__ out) {
    const int b    = blockIdx.x;
    const int y    = b >> 3;
    const int xt   = b & 7;
    const int x0   = (xt == 7) ? (OW - 64) : (xt * 64);   // 446 overlaps tile 6
    const int wave = threadIdx.x >> 6;
    const int lane = threadIdx.x & 63;
    const int l15  = lane & 15;
    const int quad = lane >> 4;

    // preload all weight fragments: wf[kpos][ch][dg]; lane holds d=wave*32+dg*16+l15,
    // c = ch*32 + quad*8 .. +7
    bf16x8 wf[9][2][2];
#pragma unroll
    for (int kpos = 0; kpos < 9; kpos++)
#pragma unroll
        for (int ch = 0; ch < 2; ch++)
#pragma unroll
            for (int dg = 0; dg < 2; dg++)
                wf[kpos][ch][dg] = *(const bf16x8*)(wt + kpos * (D_OUT * C_IN)
                                        + (wave * 32 + dg * 16 + l15) * C_IN
                                        + ch * 32 + quad * 8);

    f32x4 acc[4][2];
#pragma unroll
    for (int pxg = 0; pxg < 4; pxg++)
#pragma unroll
        for (int dg = 0; dg < 2; dg++)
            acc[pxg][dg] = (f32x4){0.f, 0.f, 0.f, 0.f};

#pragma unroll
    for (int kpos = 0; kpos < 9; kpos++) {
        const int ky = kpos / 3, kx = kpos % 3;
#pragma unroll
        for (int ch = 0; ch < 2; ch++) {
            const __bf16* base = tin + ((size_t)(y + ky) * W_IN + x0 + kx) * C_IN
                                     + ch * 32 + quad * 8;
#pragma unroll
            for (int pxg = 0; pxg < 4; pxg++) {
                // A frag: lane holds px = x0 + pxg*16 + l15 (+kx shift), c = ch*32+quad*8..+7
                bf16x8 pf = *(const bf16x8*)(base + (pxg * 16 + l15) * C_IN);
                acc[pxg][0] = __builtin_amdgcn_mfma_f32_16x16x32_bf16(pf, wf[kpos][ch][0], acc[pxg][0], 0, 0, 0);
                acc[pxg][1] = __builtin_amdgcn_mfma_f32_16x16x32_bf16(pf, wf[kpos][ch][1], acc[pxg][1], 0, 0, 0);
            }
        }
    }

    // epilogue: D layout col(l15)=d_local, row(quad*4+r)=px-in-group
#pragma unroll
    for (int pxg = 0; pxg < 4; pxg++)
#pragma unroll
        for (int dg = 0; dg < 2; dg++) {
            const int d = wave * 32 + dg * 16 + l15;
            const size_t o = (size_t)d * (OH * OW) + (size_t)y * OW + x0 + pxg * 16 + quad * 4;
            f32x2 b0 = __builtin_nontemporal_load((const f32x2*)&bias[o]);
            f32x2 b1 = __builtin_nontemporal_load((const f32x2*)&bias[o + 2]);
            f32x2 r0 = {acc[pxg][dg][0] + b0[0], acc[pxg][dg][1] + b0[1]};
            f32x2 r1 = {acc[pxg][dg][2] + b1[0], acc[pxg][dg][3] + b1[1]};
            __builtin_nontemporal_store(r0, (f32x2*)&out[o]);
            __builtin_nontemporal_store(r1, (f32x2*)&out[o + 2]);
        }
}

// ---------- fallback (proven v1) if workspace is too small ----------
#define PXT 64
#define TCOL 66
#define TCPAD 72

__global__ __launch_bounds__(256, 4)
void conv_bias_fallback(const float* __restrict__ in, const __bf16* __restrict__ wt,
                        const float* __restrict__ bias, float* __restrict__ out) {
    __shared__ __bf16 tile[3 * TCOL * TCPAD];
    const int b  = blockIdx.x;
    const int y  = b >> 3;
    const int x0 = (b & 7) * PXT;
    const int tid = threadIdx.x;
    for (int idx = tid; idx < 3 * TCOL * C_IN; idx += 256) {
        int col = idx % TCOL;
        int t   = idx / TCOL;
        int r   = t % 3;
        int c   = t / 3;
        int gx  = x0 + col;
        if (gx > W_IN - 1) gx = W_IN - 1;
        tile[(r * TCOL + col) * TCPAD + c] = (__bf16)in[(c * H_IN + (y + r)) * W_IN + gx];
    }
    __syncthreads();
    const int wave = tid >> 6, lane = tid & 63;
    const int l15 = lane & 15, quad = lane >> 4;
    const int px_base = wave * 16;
    f32x4 acc[8];
#pragma unroll
    for (int i = 0; i < 8; i++) acc[i] = (f32x4){0.f, 0.f, 0.f, 0.f};
#pragma unroll
    for (int kpos = 0; kpos < 9; kpos++) {
        const int ky = kpos / 3, kx = kpos % 3;
#pragma unroll
        for (int ch = 0; ch < 2; ch++) {
            const int c0 = ch * 32;
            bf16x8 bfrag = *(const bf16x8*)&tile[(ky * TCOL + px_base + l15 + kx) * TCPAD + c0 + quad * 8];
            const __bf16* aptr = wt + (size_t)kpos * D_OUT * C_IN + l15 * C_IN + c0 + quad * 8;
#pragma unroll
            for (int ds = 0; ds < 8; ds++) {
                bf16x8 afrag = *(const bf16x8*)(aptr + ds * 16 * C_IN);
                acc[ds] = __builtin_amdgcn_mfma_f32_16x16x32_bf16(afrag, bfrag, acc[ds], 0, 0, 0);
            }
        }
    }
    const int gx = x0 + px_base + l15;
    if (gx < OW) {
#pragma unroll
        for (int ds = 0; ds < 8; ds++) {
            const int dbase = ds * 16 + quad * 4;
#pragma unroll
            for (int r = 0; r < 4; r++) {
                const size_t o = ((size_t)(dbase + r) * OH + y) * OW + gx;
                out[o] = acc[ds][r] + bias[o];
            }
        }
    }
}

extern "C" void kernel_launch(void* const* d_in, const int* in_sizes, int n_in,
                              void* d_out, int out_size, void* d_ws, size_t ws_size,
                              hipStream_t stream) {
    const float* in   = (const float*)d_in[0];
    const float* w    = (const float*)d_in[1];
    const float* bias = (const float*)d_in[2];
    float* out = (float*)d_out;

    if (ws_size >= WS_NEEDED) {
        __bf16* tin = (__bf16*)d_ws;
        __bf16* wt  = (__bf16*)((char*)d_ws + TIN_BYTES);
        prep_weights<<<(9 * D_OUT * C_IN + 255) / 256, 256, 0, stream>>>(w, wt);
        transpose_in<<<H_IN * 2, 256, 0, stream>>>(in, tin);
        conv_main<<<OH * 8, 256, 0, stream>>>(tin, wt, bias, out);
    } else {
        __bf16* wt = (__bf16*)d_ws;
        prep_weights<<<(9 * D_OUT * C_IN + 255) / 256, 256, 0, stream>>>(w, wt);
        conv_bias_fallback<<<OH * 8, 256, 0, stream>>>(in, wt, bias, out);
    }
}

// Round 3
// 476.339 us; speedup vs baseline: 1.1844x; 1.1844x over previous
//
#include <hip/hip_runtime.h>
#include <hip/hip_bf16.h>

#define C_IN 64
#define H_IN 512
#define W_IN 512
#define D_OUT 128
#define OH 510
#define OW 510

typedef __bf16 bf16x8 __attribute__((ext_vector_type(8)));
typedef float  f32x4  __attribute__((ext_vector_type(4)));
typedef float  f32x2  __attribute__((ext_vector_type(2)));

#define TIN_ELEMS (H_IN * W_IN * C_IN)
#define TIN_BYTES ((size_t)TIN_ELEMS * 2)        // 32 MB
#define WT_BYTES  (9 * D_OUT * C_IN * 2)         // 147,456
#define WS_NEEDED (TIN_BYTES + WT_BYTES)

// ---------- pre-pass: kernels [D][C][3][3] fp32 -> wt[kpos][d][c] bf16 ----------
__global__ void prep_weights(const float* __restrict__ w, __bf16* __restrict__ wt) {
    int i = blockIdx.x * blockDim.x + threadIdx.x;
    if (i >= 9 * D_OUT * C_IN) return;
    int c    = i & 63;
    int d    = (i >> 6) & 127;
    int kpos = i >> 13;
    wt[i] = (__bf16)w[((d * C_IN) + c) * 9 + kpos];
}

// ---------- pre-pass: input [c][y][x] fp32 -> tin[y][x][c] bf16 ----------
// Block: one y, 256 px. Two 32-c chunks staged through LDS fp32 so BOTH the
// global reads (f32x4, lanes cover 256 consecutive px) and the global stores
// (bf16x8, lanes cover 16px x 32c contiguous-per-px) are coalesced.
__global__ __launch_bounds__(256, 4)
void transpose_in(const float* __restrict__ in, __bf16* __restrict__ tin) {
    __shared__ float ls[32 * 257];          // 32 c-rows, stride 257 dwords (bank-spread)
    const int b    = blockIdx.x;            // 1024
    const int y    = b >> 1;
    const int px0  = (b & 1) << 8;
    const int t    = threadIdx.x;
    const int wave = t >> 6;
    const int lane = t & 63;

    for (int cc = 0; cc < 2; cc++) {
        if (cc) __syncthreads();            // buffer reuse guard
        // phase 1: wave w loads c = cc*32 + w*8 + j, 256 px via f32x4
#pragma unroll
        for (int j = 0; j < 8; j++) {
            const int cl = wave * 8 + j;    // chunk-local c
            f32x4 v = *(const f32x4*)&in[(cc * 32 + cl) * (H_IN * W_IN) + y * W_IN + px0 + lane * 4];
            *(f32x4*)&ls[cl * 257 + lane * 4] = v;
        }
        __syncthreads();
        // phase 2: lane covers (px within 16, c-octet) so stores are contiguous
        const int oct = t & 3;              // c-octet within 32-chunk
        const int pxw = t >> 2;             // 0..63
#pragma unroll
        for (int pass = 0; pass < 4; pass++) {
            const int pxl = pass * 64 + pxw;
            bf16x8 v;
#pragma unroll
            for (int j = 0; j < 8; j++)
                v[j] = (__bf16)ls[(oct * 8 + j) * 257 + pxl];
            *(bf16x8*)&tin[((size_t)(y * W_IN) + px0 + pxl) * C_IN + cc * 32 + oct * 8] = v;
        }
    }
}

// ---------- main conv: weights pinned in registers, LDS-transposed epilogue ----------
__global__ __launch_bounds__(256, 2)
void conv_main(const __bf16* __restrict__ tin, const __bf16* __restrict__ wt,
               const float* __restrict__ bias, float* __restrict__ out) {
    __shared__ float lo[128 * 68];          // 34,816 B; stride 68 dwords
    const int b    = blockIdx.x;
    const int y    = b >> 3;
    const int xt   = b & 7;
    const int x0   = (xt == 7) ? (OW - 64) : (xt * 64);   // x0=446 overlaps tile 6 (same values)
    const int wave = threadIdx.x >> 6;
    const int lane = threadIdx.x & 63;
    const int l15  = lane & 15;
    const int quad = lane >> 4;

    // preload weight fragments; lane: d = wave*32+dg*16+l15, c = ch*32+quad*8..+7
    bf16x8 wf[9][2][2];
#pragma unroll
    for (int kpos = 0; kpos < 9; kpos++)
#pragma unroll
        for (int ch = 0; ch < 2; ch++)
#pragma unroll
            for (int dg = 0; dg < 2; dg++) {
                wf[kpos][ch][dg] = *(const bf16x8*)(wt + kpos * (D_OUT * C_IN)
                                        + (wave * 32 + dg * 16 + l15) * C_IN
                                        + ch * 32 + quad * 8);
                // pin: opaque asm use prevents the compiler from re-sinking
                // these loads into the unrolled main loop (round 2: VGPR=52
                // proved it rematerialized every load -> L2-latency-bound).
                asm volatile("" : "+v"(wf[kpos][ch][dg]));
            }

    f32x4 acc[4][2];
#pragma unroll
    for (int pxg = 0; pxg < 4; pxg++)
#pragma unroll
        for (int dg = 0; dg < 2; dg++)
            acc[pxg][dg] = (f32x4){0.f, 0.f, 0.f, 0.f};

#pragma unroll
    for (int kpos = 0; kpos < 9; kpos++) {
        const int ky = kpos / 3, kx = kpos % 3;
#pragma unroll
        for (int ch = 0; ch < 2; ch++) {
            const __bf16* base = tin + ((size_t)(y + ky) * W_IN + x0 + kx) * C_IN
                                     + ch * 32 + quad * 8;
#pragma unroll
            for (int pxg = 0; pxg < 4; pxg++) {
                bf16x8 pf = *(const bf16x8*)(base + (pxg * 16 + l15) * C_IN);
                acc[pxg][0] = __builtin_amdgcn_mfma_f32_16x16x32_bf16(pf, wf[kpos][ch][0], acc[pxg][0], 0, 0, 0);
                acc[pxg][1] = __builtin_amdgcn_mfma_f32_16x16x32_bf16(pf, wf[kpos][ch][1], acc[pxg][1], 0, 0, 0);
            }
        }
    }

    // ---- epilogue: transpose through LDS so global stores are coalesced ----
    // acc[pxg][dg][r]: px = x0+pxg*16+quad*4+r, d = wave*32+dg*16+l15
#pragma unroll
    for (int pxg = 0; pxg < 4; pxg++)
#pragma unroll
        for (int dg = 0; dg < 2; dg++) {
            const int dl = wave * 32 + dg * 16 + l15;
            *(f32x4*)&lo[dl * 68 + pxg * 16 + quad * 4] = acc[pxg][dg];
        }
    __syncthreads();
    const int xq   = threadIdx.x & 15;
    const int dgrp = threadIdx.x >> 4;      // 0..15
#pragma unroll
    for (int i = 0; i < 8; i++) {
        const int d = dgrp * 8 + i;
        f32x4 v = *(const f32x4*)&lo[d * 68 + xq * 4];
        const size_t o = (size_t)d * (OH * OW) + (size_t)y * OW + x0 + xq * 4;
        // f32x2 (8B-aligned always); f32x4 would be misaligned for odd y
        f32x2 b0 = *(const f32x2*)&bias[o];
        f32x2 b1 = *(const f32x2*)&bias[o + 2];
        f32x2 r0 = {v[0] + b0[0], v[1] + b0[1]};
        f32x2 r1 = {v[2] + b1[0], v[3] + b1[1]};
        *(f32x2*)&out[o]     = r0;
        *(f32x2*)&out[o + 2] = r1;
    }
}

// ---------- fallback (proven v1) if workspace is too small ----------
#define PXT 64
#define TCOL 66
#define TCPAD 72

__global__ __launch_bounds__(256, 4)
void conv_bias_fallback(const float* __restrict__ in, const __bf16* __restrict__ wt,
                        const float* __restrict__ bias, float* __restrict__ out) {
    __shared__ __bf16 tile[3 * TCOL * TCPAD];
    const int b  = blockIdx.x;
    const int y  = b >> 3;
    const int x0 = (b & 7) * PXT;
    const int tid = threadIdx.x;
    for (int idx = tid; idx < 3 * TCOL * C_IN; idx += 256) {
        int col = idx % TCOL;
        int t   = idx / TCOL;
        int r   = t % 3;
        int c   = t / 3;
        int gx  = x0 + col;
        if (gx > W_IN - 1) gx = W_IN - 1;
        tile[(r * TCOL + col) * TCPAD + c] = (__bf16)in[(c * H_IN + (y + r)) * W_IN + gx];
    }
    __syncthreads();
    const int wave = tid >> 6, lane = tid & 63;
    const int l15 = lane & 15, quad = lane >> 4;
    const int px_base = wave * 16;
    f32x4 acc[8];
#pragma unroll
    for (int i = 0; i < 8; i++) acc[i] = (f32x4){0.f, 0.f, 0.f, 0.f};
#pragma unroll
    for (int kpos = 0; kpos < 9; kpos++) {
        const int ky = kpos / 3, kx = kpos % 3;
#pragma unroll
        for (int ch = 0; ch < 2; ch++) {
            const int c0 = ch * 32;
            bf16x8 bfrag = *(const bf16x8*)&tile[(ky * TCOL + px_base + l15 + kx) * TCPAD + c0 + quad * 8];
            const __bf16* aptr = wt + (size_t)kpos * D_OUT * C_IN + l15 * C_IN + c0 + quad * 8;
#pragma unroll
            for (int ds = 0; ds < 8; ds++) {
                bf16x8 afrag = *(const bf16x8*)(aptr + ds * 16 * C_IN);
                acc[ds] = __builtin_amdgcn_mfma_f32_16x16x32_bf16(afrag, bfrag, acc[ds], 0, 0, 0);
            }
        }
    }
    const int gx = x0 + px_base + l15;
    if (gx < OW) {
#pragma unroll
        for (int ds = 0; ds < 8; ds++) {
            const int dbase = ds * 16 + quad * 4;
#pragma unroll
            for (int r = 0; r < 4; r++) {
                const size_t o = ((size_t)(dbase + r) * OH + y) * OW + gx;
                out[o] = acc[ds][r] + bias[o];
            }
        }
    }
}

extern "C" void kernel_launch(void* const* d_in, const int* in_sizes, int n_in,
                              void* d_out, int out_size, void* d_ws, size_t ws_size,
                              hipStream_t stream) {
    const float* in   = (const float*)d_in[0];
    const float* w    = (const float*)d_in[1];
    const float* bias = (const float*)d_in[2];
    float* out = (float*)d_out;

    if (ws_size >= WS_NEEDED) {
        __bf16* tin = (__bf16*)d_ws;
        __bf16* wt  = (__bf16*)((char*)d_ws + TIN_BYTES);
        prep_weights<<<(9 * D_OUT * C_IN + 255) / 256, 256, 0, stream>>>(w, wt);
        transpose_in<<<H_IN * 2, 256, 0, stream>>>(in, tin);
        conv_main<<<OH * 8, 256, 0, stream>>>(tin, wt, bias, out);
    } else {
        __bf16* wt = (__bf16*)d_ws;
        prep_weights<<<(9 * D_OUT * C_IN + 255) / 256, 256, 0, stream>>>(w, wt);
        conv_bias_fallback<<<OH * 8, 256, 0, stream>>>(in, wt, bias, out);
    }
}